// Round 2
// baseline (305.282 us; speedup 1.0000x reference)
//
#include <hip/hip_runtime.h>
#include <stdint.h>

#define DEV __device__ __forceinline__

typedef float f32x4 __attribute__((ext_vector_type(4)));
typedef __bf16 bf16x8 __attribute__((ext_vector_type(8)));
typedef short short8 __attribute__((ext_vector_type(8)));
typedef short short4v __attribute__((ext_vector_type(4)));

DEV unsigned short f2bf(float f) {
    union { float f; unsigned u; } c; c.f = f;
    unsigned u = c.u;
    u += 0x7fffu + ((u >> 16) & 1u);   // round-to-nearest-even
    return (unsigned short)(u >> 16);
}

DEV void async_ld16(const void* g, void* l) {
    __builtin_amdgcn_global_load_lds(
        (const __attribute__((address_space(1))) unsigned int*)g,
        (__attribute__((address_space(3))) unsigned int*)l, 16, 0, 0);
}

DEV f32x4 mfma16(bf16x8 a, bf16x8 b, f32x4 c) {
    return __builtin_amdgcn_mfma_f32_16x16x32_bf16(a, b, c, 0, 0, 0);
}

// ---------------- prep: x fp32 -> bf16 ----------------
__global__ __launch_bounds__(256) void k_cvt_x(const float* __restrict__ x,
                                               unsigned short* __restrict__ xb) {
    int t = blockIdx.x * 256 + threadIdx.x;
    const float4* xp = (const float4*)x;
    float4 a = xp[t * 2], b = xp[t * 2 + 1];
    short8 o;
    o[0] = (short)f2bf(a.x); o[1] = (short)f2bf(a.y);
    o[2] = (short)f2bf(a.z); o[3] = (short)f2bf(a.w);
    o[4] = (short)f2bf(b.x); o[5] = (short)f2bf(b.y);
    o[6] = (short)f2bf(b.z); o[7] = (short)f2bf(b.w);
    *(short8*)(xb + t * 8) = o;
}

// ---------------- prep: W [1024][3072] fp32 -> Wt [3072][1024] bf16 ----------
__global__ __launch_bounds__(256) void k_tr_w(const float* __restrict__ W,
                                              unsigned short* __restrict__ Wt) {
    __shared__ float T[64][65];
    int n0 = blockIdx.x * 64, k0 = blockIdx.y * 64;
    int t = threadIdx.x;
    int r = t >> 4, c4 = (t & 15) * 4;
    for (int i = 0; i < 4; i++) {
        int row = r + i * 16;
        float4 v = *(const float4*)(W + (k0 + row) * 3072 + n0 + c4);
        T[row][c4] = v.x; T[row][c4 + 1] = v.y; T[row][c4 + 2] = v.z; T[row][c4 + 3] = v.w;
    }
    __syncthreads();
    for (int i = 0; i < 4; i++) {
        int nrow = r + i * 16;
        short4v o;
        o[0] = (short)f2bf(T[c4 + 0][nrow]);
        o[1] = (short)f2bf(T[c4 + 1][nrow]);
        o[2] = (short)f2bf(T[c4 + 2][nrow]);
        o[3] = (short)f2bf(T[c4 + 3][nrow]);
        *(short4v*)(Wt + (n0 + nrow) * 1024 + k0 + c4) = o;
    }
}

// ---------------- QKV GEMM: [8192x1024]x[1024x3072] + bias, scatter Q/K/Vt --
// Q stored [bh][n][d]*32, K stored [bh][n][d], V stored transposed [bh][d][n]
__global__ __launch_bounds__(256, 2) void k_qkv(const unsigned short* __restrict__ xb,
                                                const unsigned short* __restrict__ Wt,
                                                const float* __restrict__ bias,
                                                unsigned short* __restrict__ Q,
                                                unsigned short* __restrict__ K,
                                                unsigned short* __restrict__ V) {
    __shared__ __align__(16) unsigned short As[128 * 64];  // XOR-swizzled chunks (mask 7)
    __shared__ __align__(16) unsigned short Bs[128 * 64];
    const int m0 = blockIdx.y * 128, n0 = blockIdx.x * 128;
    const int wave = threadIdx.x >> 6, lane = threadIdx.x & 63;
    const int wm = (wave & 1) * 64, wn = (wave >> 1) * 64;
    f32x4 acc[4][4] = {};
    const int slr = wave * 32 + (lane >> 3);  // staging local row (+ i*8)
    const int scs = lane & 7;                 // staging chunk slot

    for (int kt = 0; kt < 16; kt++) {
        __syncthreads();
        for (int i = 0; i < 4; i++) {
            int lr = slr + i * 8;
            int c = scs ^ (lr & 7);
            async_ld16(xb + (m0 + lr) * 1024 + kt * 64 + c * 8,
                       (void*)(As + (wave * 32 + i * 8) * 64));
            async_ld16(Wt + (n0 + lr) * 1024 + kt * 64 + c * 8,
                       (void*)(Bs + (wave * 32 + i * 8) * 64));
        }
        __syncthreads();
        for (int ks = 0; ks < 2; ks++) {
            bf16x8 af[4], bfr[4];
            int c0 = ks * 4 + (lane >> 4);
            for (int tm = 0; tm < 4; tm++) {
                int row = wm + tm * 16 + (lane & 15);
                af[tm] = *(const bf16x8*)(As + row * 64 + (c0 ^ (row & 7)) * 8);
            }
            for (int tn = 0; tn < 4; tn++) {
                int row = wn + tn * 16 + (lane & 15);
                bfr[tn] = *(const bf16x8*)(Bs + row * 64 + (c0 ^ (row & 7)) * 8);
            }
            for (int tm = 0; tm < 4; tm++)
                for (int tn = 0; tn < 4; tn++)
                    acc[tm][tn] = mfma16(af[tm], bfr[tn], acc[tm][tn]);
        }
    }

    // epilogue: bias + scatter. col -> (h = c/192, d = (c%192)/3, which = c%3)
    const int batch = m0 >> 11;
    for (int tn = 0; tn < 4; tn++) {
        int col = n0 + wn + tn * 16 + (lane & 15);
        int h = col / 192;
        int rem = col - h * 192;
        int d = rem / 3;
        int which = rem - d * 3;
        float bv = bias[col];
        int bh = batch * 16 + h;
        unsigned qk_base = (unsigned)bh * 131072u + (unsigned)d;
        unsigned v_base = ((unsigned)bh * 64u + (unsigned)d) * 2048u;
        unsigned short* dst = which == 0 ? Q : (which == 1 ? K : V);
        float mult = which == 0 ? 32.0f : 1.0f;  // fold attn scale sqrt(1024)=32 into Q
        for (int tm = 0; tm < 4; tm++) {
            int rbase = m0 + wm + tm * 16 + ((lane >> 4) * 4);
            for (int r = 0; r < 4; r++) {
                int row = rbase + r;
                unsigned token = (unsigned)(row & 2047);
                float val = (acc[tm][tn][r] + bv) * mult;
                unsigned idx = (which == 2) ? (v_base + token) : (qk_base + token * 64u);
                dst[idx] = f2bf(val);
            }
        }
    }
}

// ---------------- fused attention: O = (Q*32 . K^T) . V, no softmax ---------
// Barrier-free K-loop. wave = (q-half, key-half). K/V fragments direct from
// global (L2-resident). S^T computed via swapped mfma operands so each lane's
// 4 acc regs are 4 consecutive keys -> one b64 LDS write, XOR-swizzled.
__global__ __launch_bounds__(256, 2) void k_attn(const unsigned short* __restrict__ Q,
                                                 const unsigned short* __restrict__ K,
                                                 const unsigned short* __restrict__ V,
                                                 float* __restrict__ out) {
    __shared__ __align__(16) unsigned short Ss[4][64 * 64];  // per-wave S, 8KB each
    const int bh = blockIdx.y;
    const int q0 = blockIdx.x * 128;
    const int wave = threadIdx.x >> 6, lane = threadIdx.x & 63;
    const int qh = wave & 1, kh = wave >> 1;
    const unsigned base = (unsigned)bh * 131072u;
    const int lan15 = lane & 15, quad = lane >> 4;
    const int wq0 = q0 + qh * 64;

    // Q B-operand fragments, resident all kernel: B[n=q][k=d]
    bf16x8 qf[4][2];
    for (int nt = 0; nt < 4; nt++)
        for (int ks = 0; ks < 2; ks++)
            qf[nt][ks] = *(const bf16x8*)(Q + base +
                          (unsigned)(wq0 + nt * 16 + lan15) * 64u + ks * 32 + quad * 8);

    unsigned short* Sw = Ss[wave];
    f32x4 oacc[4][4] = {};
    bf16x8 kb[4][2], bv[4][2];

    // j-tile = 128 keys; this wave covers keys [j*128 + kh*64, +64)
#define LOAD_KB(J) do { \
        unsigned kbase = base + (unsigned)(((J) * 128 + kh * 64)) * 64u; \
        for (int mt = 0; mt < 4; mt++) \
            for (int ks = 0; ks < 2; ks++) \
                kb[mt][ks] = *(const bf16x8*)(K + kbase + \
                    (unsigned)(mt * 16 + lan15) * 64u + ks * 32 + quad * 8); \
    } while (0)
#define LOAD_BV(J) do { \
        unsigned tb = (unsigned)((J) * 128 + kh * 64); \
        for (int nt = 0; nt < 4; nt++) \
            for (int ks2 = 0; ks2 < 2; ks2++) \
                bv[nt][ks2] = *(const bf16x8*)(V + base + \
                    (unsigned)(nt * 16 + lan15) * 2048u + tb + ks2 * 32 + quad * 8); \
    } while (0)

    LOAD_KB(0);
    LOAD_BV(0);

    for (int j = 0; j < 16; j++) {
        // ---- S^T phase: D[m=key][n=q] = K . Q^T (A=K frag, B=Q frag) ----
        for (int mt = 0; mt < 4; mt++)
            for (int nt = 0; nt < 4; nt++) {
                f32x4 s = {};
                s = mfma16(kb[mt][0], qf[nt][0], s);
                s = mfma16(kb[mt][1], qf[nt][1], s);
                // lane holds keys mt*16+quad*4+[0,4), q = nt*16+lan15
                int q = nt * 16 + lan15;
                int c4 = (mt * 4 + quad) ^ (q & 15);   // 4-elem chunk XOR swizzle
                uint2 p;
                p.x = (unsigned)f2bf(s[0]) | ((unsigned)f2bf(s[1]) << 16);
                p.y = (unsigned)f2bf(s[2]) | ((unsigned)f2bf(s[3]) << 16);
                *(uint2*)(Sw + q * 64 + c4 * 4) = p;
            }
        if (j < 15) LOAD_KB(j + 1);   // refill dead kb regs, hidden behind PV

        // ---- PV phase: O[q][d] += S[q][key] . V^T[d][key] ----
        for (int ks2 = 0; ks2 < 2; ks2++) {
            bf16x8 aS[4];
            for (int tm = 0; tm < 4; tm++) {
                int q = tm * 16 + lan15;
                int cA = ks2 * 8 + quad * 2;
                uint2 u0 = *(const uint2*)(Sw + q * 64 + ((cA) ^ (q & 15)) * 4);
                uint2 u1 = *(const uint2*)(Sw + q * 64 + ((cA + 1) ^ (q & 15)) * 4);
                union { uint4 u; bf16x8 v; } cv;
                cv.u.x = u0.x; cv.u.y = u0.y; cv.u.z = u1.x; cv.u.w = u1.y;
                aS[tm] = cv.v;
            }
            for (int tm = 0; tm < 4; tm++)
                for (int tn = 0; tn < 4; tn++)
                    oacc[tm][tn] = mfma16(aS[tm], bv[tn][ks2], oacc[tm][tn]);
        }
        if (j < 15) LOAD_BV(j + 1);   // refill dead bv regs, hidden behind next S
    }
#undef LOAD_KB
#undef LOAD_BV

    // ---- cross-wave key-half reduction (waves w and w+2 share q-half) ----
    float* red = (float*)Ss;  // 32KB: exactly 2 waves x 16 tiles x 64 lanes x 16B
    __syncthreads();          // waves 0/1 done reading their Sw
    if (wave >= 2) {
        for (int tm = 0; tm < 4; tm++)
            for (int tn = 0; tn < 4; tn++)
                *(f32x4*)(red + (((wave - 2) * 16 + tm * 4 + tn) * 64 + lane) * 4) =
                    oacc[tm][tn];
    }
    __syncthreads();
    if (wave < 2) {
        for (int tm = 0; tm < 4; tm++)
            for (int tn = 0; tn < 4; tn++) {
                f32x4 part = *(const f32x4*)(red + ((wave * 16 + tm * 4 + tn) * 64 + lane) * 4);
                f32x4 o = oacc[tm][tn];
                o.x += part.x; o.y += part.y; o.z += part.z; o.w += part.w;
                int rb = wq0 + tm * 16 + quad * 4;
                int col = tn * 16 + lan15;
                for (int r = 0; r < 4; r++)
                    out[base + (unsigned)(rb + r) * 64u + col] = o[r];
            }
    }
}

extern "C" void kernel_launch(void* const* d_in, const int* in_sizes, int n_in,
                              void* d_out, int out_size, void* d_ws, size_t ws_size,
                              hipStream_t stream) {
    const float* x = (const float*)d_in[0];
    const float* W = (const float*)d_in[1];
    const float* b = (const float*)d_in[2];
    float* out = (float*)d_out;

    unsigned short* xb = (unsigned short*)d_ws;   // 8,388,608 bf16
    unsigned short* Wt = xb + 8388608;            // 3,145,728 bf16
    unsigned short* Qb = Wt + 3145728;            // 8,388,608 bf16 (scaled by 32)
    unsigned short* Kb = Qb + 8388608;            // 8,388,608 bf16
    unsigned short* Vb = Kb + 8388608;            // 8,388,608 bf16, [bh][d][n]
    // total workspace: 73,400,320 bytes

    k_cvt_x<<<4096, 256, 0, stream>>>(x, xb);
    k_tr_w<<<dim3(48, 16), 256, 0, stream>>>(W, Wt);
    k_qkv<<<dim3(24, 64), 256, 0, stream>>>(xb, Wt, b, Qb, Kb, Vb);
    k_attn<<<dim3(16, 64), 256, 0, stream>>>(Qb, Kb, Vb, out);
}

// Round 3
// 200.647 us; speedup vs baseline: 1.5215x; 1.5215x over previous
//
#include <hip/hip_runtime.h>
#include <stdint.h>

#define DEV __device__ __forceinline__

typedef float f32x4 __attribute__((ext_vector_type(4)));
typedef __bf16 bf16x8 __attribute__((ext_vector_type(8)));
typedef short short8 __attribute__((ext_vector_type(8)));
typedef short short4v __attribute__((ext_vector_type(4)));

DEV unsigned short f2bf(float f) {
    union { float f; unsigned u; } c; c.f = f;
    unsigned u = c.u;
    u += 0x7fffu + ((u >> 16) & 1u);   // round-to-nearest-even
    return (unsigned short)(u >> 16);
}

DEV void async_ld16(const void* g, void* l) {
    __builtin_amdgcn_global_load_lds(
        (const __attribute__((address_space(1))) unsigned int*)g,
        (__attribute__((address_space(3))) unsigned int*)l, 16, 0, 0);
}

DEV f32x4 mfma16(bf16x8 a, bf16x8 b, f32x4 c) {
    return __builtin_amdgcn_mfma_f32_16x16x32_bf16(a, b, c, 0, 0, 0);
}

// ---------------- prep: x fp32 -> bf16 ----------------
__global__ __launch_bounds__(256) void k_cvt_x(const float* __restrict__ x,
                                               unsigned short* __restrict__ xb) {
    int t = blockIdx.x * 256 + threadIdx.x;
    const float4* xp = (const float4*)x;
    float4 a = xp[t * 2], b = xp[t * 2 + 1];
    short8 o;
    o[0] = (short)f2bf(a.x); o[1] = (short)f2bf(a.y);
    o[2] = (short)f2bf(a.z); o[3] = (short)f2bf(a.w);
    o[4] = (short)f2bf(b.x); o[5] = (short)f2bf(b.y);
    o[6] = (short)f2bf(b.z); o[7] = (short)f2bf(b.w);
    *(short8*)(xb + t * 8) = o;
}

// ---------------- prep: W [1024][3072] fp32 -> Wt [3072][1024] bf16 ----------
__global__ __launch_bounds__(256) void k_tr_w(const float* __restrict__ W,
                                              unsigned short* __restrict__ Wt) {
    __shared__ float T[64][65];
    int n0 = blockIdx.x * 64, k0 = blockIdx.y * 64;
    int t = threadIdx.x;
    int r = t >> 4, c4 = (t & 15) * 4;
    for (int i = 0; i < 4; i++) {
        int row = r + i * 16;
        float4 v = *(const float4*)(W + (k0 + row) * 3072 + n0 + c4);
        T[row][c4] = v.x; T[row][c4 + 1] = v.y; T[row][c4 + 2] = v.z; T[row][c4 + 3] = v.w;
    }
    __syncthreads();
    for (int i = 0; i < 4; i++) {
        int nrow = r + i * 16;
        short4v o;
        o[0] = (short)f2bf(T[c4 + 0][nrow]);
        o[1] = (short)f2bf(T[c4 + 1][nrow]);
        o[2] = (short)f2bf(T[c4 + 2][nrow]);
        o[3] = (short)f2bf(T[c4 + 3][nrow]);
        *(short4v*)(Wt + (n0 + nrow) * 1024 + k0 + c4) = o;
    }
}

// ---------------- QKV GEMM: [8192x1024]x[1024x3072] + bias, scatter --------
// Q stored [bh][n][d] scaled x32; K,V stored transposed [bh][d][n]
__global__ __launch_bounds__(256, 2) void k_qkv(const unsigned short* __restrict__ xb,
                                                const unsigned short* __restrict__ Wt,
                                                const float* __restrict__ bias,
                                                unsigned short* __restrict__ Q,
                                                unsigned short* __restrict__ K,
                                                unsigned short* __restrict__ V) {
    __shared__ __align__(16) unsigned short As[128 * 64];  // XOR-swizzled chunks (mask 7)
    __shared__ __align__(16) unsigned short Bs[128 * 64];
    const int m0 = blockIdx.y * 128, n0 = blockIdx.x * 128;
    const int wave = threadIdx.x >> 6, lane = threadIdx.x & 63;
    const int wm = (wave & 1) * 64, wn = (wave >> 1) * 64;
    f32x4 acc[4][4] = {};
    const int slr = wave * 32 + (lane >> 3);  // staging local row (+ i*8)
    const int scs = lane & 7;                 // staging chunk slot

    for (int kt = 0; kt < 16; kt++) {
        __syncthreads();
        for (int i = 0; i < 4; i++) {
            int lr = slr + i * 8;
            int c = scs ^ (lr & 7);
            async_ld16(xb + (m0 + lr) * 1024 + kt * 64 + c * 8,
                       (void*)(As + (wave * 32 + i * 8) * 64));
            async_ld16(Wt + (n0 + lr) * 1024 + kt * 64 + c * 8,
                       (void*)(Bs + (wave * 32 + i * 8) * 64));
        }
        __syncthreads();
        for (int ks = 0; ks < 2; ks++) {
            bf16x8 af[4], bfr[4];
            int c0 = ks * 4 + (lane >> 4);
            for (int tm = 0; tm < 4; tm++) {
                int row = wm + tm * 16 + (lane & 15);
                af[tm] = *(const bf16x8*)(As + row * 64 + (c0 ^ (row & 7)) * 8);
            }
            for (int tn = 0; tn < 4; tn++) {
                int row = wn + tn * 16 + (lane & 15);
                bfr[tn] = *(const bf16x8*)(Bs + row * 64 + (c0 ^ (row & 7)) * 8);
            }
            for (int tm = 0; tm < 4; tm++)
                for (int tn = 0; tn < 4; tn++)
                    acc[tm][tn] = mfma16(af[tm], bfr[tn], acc[tm][tn]);
        }
    }

    // epilogue: bias + scatter. col -> (h = c/192, d = (c%192)/3, which = c%3)
    const int batch = m0 >> 11;
    for (int tn = 0; tn < 4; tn++) {
        int col = n0 + wn + tn * 16 + (lane & 15);
        int h = col / 192;
        int rem = col - h * 192;
        int d = rem / 3;
        int which = rem - d * 3;
        float bv = bias[col];
        int bh = batch * 16 + h;
        unsigned q_base = (unsigned)bh * 131072u + (unsigned)d;          // [bh][n][d]
        unsigned kv_base = ((unsigned)bh * 64u + (unsigned)d) * 2048u;   // [bh][d][n]
        unsigned short* dst = which == 0 ? Q : (which == 1 ? K : V);
        float mult = which == 0 ? 32.0f : 1.0f;  // fold attn scale sqrt(1024)=32 into Q
        for (int tm = 0; tm < 4; tm++) {
            int rbase = m0 + wm + tm * 16 + ((lane >> 4) * 4);
            for (int r = 0; r < 4; r++) {
                int row = rbase + r;
                unsigned token = (unsigned)(row & 2047);
                float val = (acc[tm][tn][r] + bv) * mult;
                unsigned idx = (which == 0) ? (q_base + token * 64u) : (kv_base + token);
                dst[idx] = f2bf(val);
            }
        }
    }
}

// ---------------- k_kv: Mpart[bh][ns] = K^T V over n-range ns*512..+512 ----
// Kt,Vt are [bh][d][n]. M[d1][d2] = sum_n K[n][d1] V[n][d2]. fp32 partials,
// stored in raw MFMA C-layout: flat e = (tile*64+lane)*4 + r.
__global__ __launch_bounds__(256) void k_kv(const unsigned short* __restrict__ Kt,
                                            const unsigned short* __restrict__ Vt,
                                            float* __restrict__ Mpart) {
    __shared__ __align__(16) float Ss[3][4096];
    const int bh = blockIdx.y, ns = blockIdx.x;
    const int wave = threadIdx.x >> 6, lane = threadIdx.x & 63;
    const int lan15 = lane & 15, quad = lane >> 4;
    const unsigned base = (unsigned)bh * 131072u;
    const int n0w = ns * 512 + wave * 128;
    f32x4 acc[4][4] = {};
#pragma unroll
    for (int ks = 0; ks < 4; ks++) {
        bf16x8 af[4], bfr[4];
        int no = n0w + ks * 32 + quad * 8;
        for (int mt = 0; mt < 4; mt++)
            af[mt] = *(const bf16x8*)(Kt + base + (unsigned)(mt * 16 + lan15) * 2048u + no);
        for (int nt = 0; nt < 4; nt++)
            bfr[nt] = *(const bf16x8*)(Vt + base + (unsigned)(nt * 16 + lan15) * 2048u + no);
        for (int mt = 0; mt < 4; mt++)
            for (int nt = 0; nt < 4; nt++)
                acc[mt][nt] = mfma16(af[mt], bfr[nt], acc[mt][nt]);
    }
    if (wave >= 1) {
        for (int mt = 0; mt < 4; mt++)
            for (int nt = 0; nt < 4; nt++)
                *(f32x4*)(&Ss[wave - 1][((mt * 4 + nt) * 64 + lane) * 4]) = acc[mt][nt];
    }
    __syncthreads();
    if (wave == 0) {
        float* dst = Mpart + ((unsigned)bh * 4u + (unsigned)ns) * 4096u;
        for (int mt = 0; mt < 4; mt++)
            for (int nt = 0; nt < 4; nt++) {
                f32x4 o = acc[mt][nt];
                for (int s = 0; s < 3; s++) {
                    f32x4 p = *(const f32x4*)(&Ss[s][((mt * 4 + nt) * 64 + lane) * 4]);
                    o.x += p.x; o.y += p.y; o.z += p.z; o.w += p.w;
                }
                *(f32x4*)(dst + ((mt * 4 + nt) * 64 + lane) * 4) = o;
            }
    }
}

// ---------------- k_qm: out[bh][n][d2] = Q(x32)[bh][n][d1] . M[d1][d2] -----
__global__ __launch_bounds__(256, 2) void k_qm(const unsigned short* __restrict__ Q,
                                               const float* __restrict__ Mpart,
                                               float* __restrict__ out) {
    __shared__ __align__(16) unsigned short Msb[64 * 64];  // [d2][d1 xor-swizzled], 8KB
    const int bh = blockIdx.y;
    const int q0 = blockIdx.x * 256;
    const int t = threadIdx.x;
    const int wave = t >> 6, lane = t & 63;
    const int lan15 = lane & 15, quad = lane >> 4;
    const unsigned base = (unsigned)bh * 131072u;

    // sum the 4 fp32 partials, decode C-layout -> (d1,d2), store bf16 transposed
    {
        const float* mp = Mpart + (unsigned)bh * 4u * 4096u;
        int e0 = t * 16;
        for (int j = 0; j < 4; j++) {
            f32x4 m = *(const f32x4*)(mp + e0 + j * 4);
            for (int s = 1; s < 4; s++) {
                f32x4 p = *(const f32x4*)(mp + s * 4096 + e0 + j * 4);
                m.x += p.x; m.y += p.y; m.z += p.z; m.w += p.w;
            }
            for (int r = 0; r < 4; r++) {
                int e = e0 + j * 4 + r;
                int tile = e >> 8, le = (e >> 2) & 63;
                int d1 = (tile >> 2) * 16 + ((le >> 4) << 2) + r;
                int d2 = (tile & 3) * 16 + (le & 15);
                Msb[d2 * 64 + (((d1 >> 3) ^ (d2 & 7)) << 3) + (d1 & 7)] = f2bf(m[r]);
            }
        }
    }
    __syncthreads();

    const int q0w = q0 + wave * 64;
    f32x4 oacc[4][4] = {};
#pragma unroll
    for (int ks = 0; ks < 2; ks++) {
        bf16x8 af[4], bfr[4];
        for (int mt = 0; mt < 4; mt++)
            af[mt] = *(const bf16x8*)(Q + base + (unsigned)(q0w + mt * 16 + lan15) * 64u +
                                      ks * 32 + quad * 8);
        for (int nt = 0; nt < 4; nt++) {
            int d2 = nt * 16 + lan15;
            bfr[nt] = *(const bf16x8*)(Msb + d2 * 64 + (((ks * 4 + quad) ^ (d2 & 7)) << 3));
        }
        for (int mt = 0; mt < 4; mt++)
            for (int nt = 0; nt < 4; nt++)
                oacc[mt][nt] = mfma16(af[mt], bfr[nt], oacc[mt][nt]);
    }
    for (int mt = 0; mt < 4; mt++)
        for (int nt = 0; nt < 4; nt++)
            for (int r = 0; r < 4; r++)
                out[base + (unsigned)(q0w + mt * 16 + quad * 4 + r) * 64u + nt * 16 + lan15] =
                    oacc[mt][nt][r];
}

extern "C" void kernel_launch(void* const* d_in, const int* in_sizes, int n_in,
                              void* d_out, int out_size, void* d_ws, size_t ws_size,
                              hipStream_t stream) {
    const float* x = (const float*)d_in[0];
    const float* W = (const float*)d_in[1];
    const float* b = (const float*)d_in[2];
    float* out = (float*)d_out;

    unsigned short* xb = (unsigned short*)d_ws;   // 8,388,608 bf16
    unsigned short* Wt = xb + 8388608;            // 3,145,728 bf16
    unsigned short* Qb = Wt + 3145728;            // 8,388,608 bf16 (scaled by 32)
    unsigned short* Kt = Qb + 8388608;            // 8,388,608 bf16, [bh][d][n]
    unsigned short* Vt = Kt + 8388608;            // 8,388,608 bf16, [bh][d][n]
    // Mpart aliases the xb region: xb is dead after k_qkv completes (stream order)
    float* Mpart = (float*)d_ws;                  // 64*4*4096 fp32 = 4 MB
    // total workspace: 73,400,320 bytes

    k_cvt_x<<<4096, 256, 0, stream>>>(x, xb);
    k_tr_w<<<dim3(48, 16), 256, 0, stream>>>(W, Wt);
    k_qkv<<<dim3(24, 64), 256, 0, stream>>>(xb, Wt, b, Qb, Kt, Vt);
    k_kv<<<dim3(4, 64), 256, 0, stream>>>(Kt, Vt, Mpart);
    k_qm<<<dim3(8, 64), 256, 0, stream>>>(Qb, Mpart, out);
}